// Round 8
// baseline (119.747 us; speedup 1.0000x reference)
//
#include <hip/hip_runtime.h>
#include <math.h>

namespace {

using bf16x8 = __attribute__((ext_vector_type(8))) short;
using f32x4  = __attribute__((ext_vector_type(4))) float;

constexpr int D   = 40;     // n_embed
constexpr int HS  = 10;     // head size
constexpr int NH  = 4;      // heads
constexpr int TT  = 2048;   // seq len
constexpr int BB  = 16;     // batch
constexpr int ROWS = BB * TT;       // 32768
constexpr int PE  = 16;             // padded head size for q/k bf16 rows
constexpr int VR  = 11;             // vT rows: 10 V + 1 ones (for l via MFMA)
constexpr float LOG2E = 1.4426950408889634f;

__device__ inline unsigned short f2b(float x) {   // fp32 -> bf16 RNE
    unsigned int u = __float_as_uint(x);
    unsigned int r = (u + 0x7fffu + ((u >> 16) & 1u)) >> 16;
    return (unsigned short)r;
}

__device__ inline f32x4 mfma32(bf16x8 a, bf16x8 b, f32x4 c) {
    return __builtin_amdgcn_mfma_f32_16x16x32_bf16(a, b, c, 0, 0, 0);
}

__device__ inline float dot40(const float* __restrict__ xr,
                              const float* __restrict__ w) {
    float s0 = 0.f, s1 = 0.f, s2 = 0.f, s3 = 0.f;
    const float4* w4 = reinterpret_cast<const float4*>(w);
    #pragma unroll
    for (int i = 0; i < 10; ++i) {
        float4 t = w4[i];
        s0 = fmaf(xr[4*i+0], t.x, s0);
        s1 = fmaf(xr[4*i+1], t.y, s1);
        s2 = fmaf(xr[4*i+2], t.z, s2);
        s3 = fmaf(xr[4*i+3], t.w, s3);
    }
    return (s0 + s1) + (s2 + s3);
}

// ---------------- Kernel 1: LN1 + QKV projection, thread per (row, head) ----
__global__ __launch_bounds__(256) void k_ln_qkv(
    const float* __restrict__ x,  const float* __restrict__ Wq,
    const float* __restrict__ Wk, const float* __restrict__ Wv,
    const float* __restrict__ g1, const float* __restrict__ be1,
    float* __restrict__ xn, unsigned short* __restrict__ qb,
    unsigned short* __restrict__ kb, unsigned short* __restrict__ vT)
{
    __shared__ float wt_s[3*NH*HS*D];   // transposed: [which][h][e][d]
    __shared__ float g_s[D], b_s[D];
    const int tid = threadIdx.x;
    for (int i = tid; i < NH*D*HS; i += 256) {
        const int h = i / (D*HS), r = i % (D*HS);
        const int d = r / HS, e = r % HS;
        const int to = (h*HS + e)*D + d;
        wt_s[to]              = Wq[i];
        wt_s[NH*HS*D + to]    = Wk[i];
        wt_s[2*NH*HS*D + to]  = Wv[i];
    }
    if (tid < D) { g_s[tid] = g1[tid]; b_s[tid] = be1[tid]; }
    __syncthreads();

    const int gid = blockIdx.x * 256 + tid;
    const int row = gid >> 2;
    const int h   = gid & 3;

    float xr[D];
    const float4* xp = reinterpret_cast<const float4*>(x + (size_t)row * D);
    #pragma unroll
    for (int i = 0; i < D/4; ++i) {
        float4 t4 = xp[i];
        xr[4*i+0]=t4.x; xr[4*i+1]=t4.y; xr[4*i+2]=t4.z; xr[4*i+3]=t4.w;
    }
    float mu = 0.f;
    #pragma unroll
    for (int d = 0; d < D; ++d) mu += xr[d];
    mu *= (1.f/D);
    float var = 0.f;
    #pragma unroll
    for (int d = 0; d < D; ++d) { float dd = xr[d]-mu; var += dd*dd; }
    var *= (1.f/D);
    const float rs = rsqrtf(var + 1e-5f);
    #pragma unroll
    for (int d = 0; d < D; ++d) xr[d] = (xr[d]-mu)*rs*g_s[d] + b_s[d];

    if (h == 0) {
        float4* xo = reinterpret_cast<float4*>(xn + (size_t)row * D);
        #pragma unroll
        for (int i = 0; i < D/4; ++i) {
            float4 t4; t4.x=xr[4*i+0]; t4.y=xr[4*i+1]; t4.z=xr[4*i+2]; t4.w=xr[4*i+3];
            xo[i] = t4;
        }
    }

    const int b = row >> 11;
    const int t = row & (TT-1);
    const int bh = b*NH + h;

    float aq[HS], ak[HS], av[HS];
    #pragma unroll
    for (int e = 0; e < HS; ++e) {
        aq[e] = dot40(xr, &wt_s[(h*HS + e)*D]);
        ak[e] = dot40(xr, &wt_s[NH*HS*D + (h*HS + e)*D]);
        av[e] = dot40(xr, &wt_s[2*NH*HS*D + (h*HS + e)*D]);
    }

    union { unsigned short u[PE]; uint4 v4[2]; } Uq, Uk;
    #pragma unroll
    for (int e = 0; e < PE; ++e) {
        // fold log2(e) into q so attention can use exp2 directly
        Uq.u[e] = (e < HS) ? f2b(aq[e] * LOG2E) : (unsigned short)0;
        Uk.u[e] = (e < HS) ? f2b(ak[e]) : (unsigned short)0;
    }
    uint4* qp4 = reinterpret_cast<uint4*>(qb + ((size_t)bh*TT + t)*PE);
    uint4* kp4 = reinterpret_cast<uint4*>(kb + ((size_t)bh*TT + t)*PE);
    qp4[0] = Uq.v4[0]; qp4[1] = Uq.v4[1];
    kp4[0] = Uk.v4[0]; kp4[1] = Uk.v4[1];
    #pragma unroll
    for (int e = 0; e < HS; ++e)
        vT[((size_t)bh*VR + e)*TT + t] = f2b(av[e]);
    vT[((size_t)bh*VR + HS)*TT + t] = 0x3F80;   // ones row -> l via MFMA
}

// ---------------- Kernel 2: MFMA flash attention, dual j-stream ILP ---------
// Verified 16x16x32 layouts only. Each wave: 16 i-rows, TWO independent
// j-streams (j in [0,1024) and [1024,2048)), separate PT buffers + accs ->
// two independent dep chains fill each other's stall slots. acc=accA+accB
// exact (no max-tracking; l additive via ones-row of V^T, output row 10).
__global__ __launch_bounds__(256, 4) void k_attn(
    const unsigned short* __restrict__ qb, const unsigned short* __restrict__ kb,
    const unsigned short* __restrict__ vT, float* __restrict__ ao)
{
    __shared__ __align__(16) unsigned short PT[4][2][16][40];  // 80B rows: ~2-way banks
    const int w    = threadIdx.x >> 6;
    const int lane = threadIdx.x & 63;
    const int g    = lane >> 4;
    const int li   = lane & 15;
    const int bh   = blockIdx.y;
    const int i0   = blockIdx.x * 64 + w * 16;
    const size_t bT = (size_t)bh * TT;

    const bf16x8 zero8 = {0,0,0,0,0,0,0,0};
    const f32x4  zacc  = {0.f,0.f,0.f,0.f};

    bf16x8 kf = zero8;                       // B-frag: k[i0+li][8g..8g+7]
    if (g < 2) kf = *reinterpret_cast<const bf16x8*>(kb + (bT + i0 + li)*PE + 8*g);

    f32x4 accA = zacc, accB = zacc;
    const unsigned short* vrow = vT + ((size_t)bh*VR + (li <= HS ? li : 0))*TT;
    const unsigned short* qrow = qb + (bT + li)*PE + 8*g;   // used by g<2 lanes

    for (int it = 0; it < TT/64; ++it) {     // 32 iterations, 64 j each
        const int jA = it * 32;
        const int jB = jA + TT/2;

        // -------- all global loads up front (independent of MFMA chains) ----
        bf16x8 a0A=zero8, a1A=zero8, a0B=zero8, a1B=zero8;
        if (g < 2) {
            a0A = *reinterpret_cast<const bf16x8*>(qrow + (size_t)(jA     )*PE);
            a1A = *reinterpret_cast<const bf16x8*>(qrow + (size_t)(jA + 16)*PE);
            a0B = *reinterpret_cast<const bf16x8*>(qrow + (size_t)(jB     )*PE);
            a1B = *reinterpret_cast<const bf16x8*>(qrow + (size_t)(jB + 16)*PE);
        }
        bf16x8 vfA=zero8, vfB=zero8;
        if (li <= HS) {
            vfA = *reinterpret_cast<const bf16x8*>(vrow + jA + 8*g);
            vfB = *reinterpret_cast<const bf16x8*>(vrow + jB + 8*g);
        }

        // -------- scores (2 per stream) ------------------------------------
        f32x4 sA0 = mfma32(a0A, kf, zacc);   // S^T[jA+4g+r][i0+li]
        f32x4 sA1 = mfma32(a1A, kf, zacc);   // S^T[jA+16+4g+r][..]
        f32x4 sB0 = mfma32(a0B, kf, zacc);
        f32x4 sB1 = mfma32(a1B, kf, zacc);

        // -------- exp2 + pack (q pre-scaled by log2 e) ---------------------
        const float pA0 = __builtin_amdgcn_exp2f(sA0[0]), pA1 = __builtin_amdgcn_exp2f(sA0[1]);
        const float pA2 = __builtin_amdgcn_exp2f(sA0[2]), pA3 = __builtin_amdgcn_exp2f(sA0[3]);
        const float pA4 = __builtin_amdgcn_exp2f(sA1[0]), pA5 = __builtin_amdgcn_exp2f(sA1[1]);
        const float pA6 = __builtin_amdgcn_exp2f(sA1[2]), pA7 = __builtin_amdgcn_exp2f(sA1[3]);
        const float pB0 = __builtin_amdgcn_exp2f(sB0[0]), pB1 = __builtin_amdgcn_exp2f(sB0[1]);
        const float pB2 = __builtin_amdgcn_exp2f(sB0[2]), pB3 = __builtin_amdgcn_exp2f(sB0[3]);
        const float pB4 = __builtin_amdgcn_exp2f(sB1[0]), pB5 = __builtin_amdgcn_exp2f(sB1[1]);
        const float pB6 = __builtin_amdgcn_exp2f(sB1[2]), pB7 = __builtin_amdgcn_exp2f(sB1[3]);

        unsigned int wA0,wA1,wA2,wA3, wB0,wB1,wB2,wB3;
        asm("v_cvt_pk_bf16_f32 %0, %1, %2" : "=v"(wA0) : "v"(pA0), "v"(pA1));
        asm("v_cvt_pk_bf16_f32 %0, %1, %2" : "=v"(wA1) : "v"(pA2), "v"(pA3));
        asm("v_cvt_pk_bf16_f32 %0, %1, %2" : "=v"(wA2) : "v"(pA4), "v"(pA5));
        asm("v_cvt_pk_bf16_f32 %0, %1, %2" : "=v"(wA3) : "v"(pA6), "v"(pA7));
        asm("v_cvt_pk_bf16_f32 %0, %1, %2" : "=v"(wB0) : "v"(pB0), "v"(pB1));
        asm("v_cvt_pk_bf16_f32 %0, %1, %2" : "=v"(wB1) : "v"(pB2), "v"(pB3));
        asm("v_cvt_pk_bf16_f32 %0, %1, %2" : "=v"(wB2) : "v"(pB4), "v"(pB5));
        asm("v_cvt_pk_bf16_f32 %0, %1, %2" : "=v"(wB3) : "v"(pB6), "v"(pB7));

        // -------- P^T bounce: wave-private LDS, in-order DS => no barrier ---
        *reinterpret_cast<uint2*>(&PT[w][0][li][4*g])      = make_uint2(wA0, wA1);
        *reinterpret_cast<uint2*>(&PT[w][0][li][16 + 4*g]) = make_uint2(wA2, wA3);
        *reinterpret_cast<uint2*>(&PT[w][1][li][4*g])      = make_uint2(wB0, wB1);
        *reinterpret_cast<uint2*>(&PT[w][1][li][16 + 4*g]) = make_uint2(wB2, wB3);

        bf16x8 pfA = *reinterpret_cast<const bf16x8*>(&PT[w][0][li][8*g]);
        bf16x8 pfB = *reinterpret_cast<const bf16x8*>(&PT[w][1][li][8*g]);

        // -------- PV (1 per stream) ----------------------------------------
        accA = mfma32(vfA, pfA, accA);       // O^T[e=4g+r][i0+li]
        accB = mfma32(vfB, pfB, accB);
    }

    const f32x4 acc = accA + accB;
    // l for column li = O^T row 10 = lane (g=2, li), reg 2
    const float l = __shfl(acc[2], 32 + li);
    const float linv = 1.f / l;
    float* orow = ao + (bT + i0 + li) * HS;
    #pragma unroll
    for (int r = 0; r < 4; ++r) {
        const int e = 4*g + r;
        if (e < HS) orow[e] = acc[r] * linv;
    }
}

// ---------------- Kernel 3: epilogue, 2 threads per row ----------------
__global__ __launch_bounds__(256) void k_epilogue(
    const float* __restrict__ attn, const float* __restrict__ xn,
    const float* __restrict__ Wp, const float* __restrict__ bp,
    const float* __restrict__ W1, const float* __restrict__ b1,
    const float* __restrict__ W2, const float* __restrict__ b2,
    const float* __restrict__ g2, const float* __restrict__ be2,
    float* __restrict__ out)
{
    __shared__ float wp_s[D*D], w1_s[D*D], w2_s[D*D];
    __shared__ float bp_s[D], b1_s[D], b2_s[D], g_s[D], be_s[D];
    const int tid = threadIdx.x;
    for (int i = tid; i < D*D; i += 256) { wp_s[i]=Wp[i]; w1_s[i]=W1[i]; w2_s[i]=W2[i]; }
    if (tid < D) {
        bp_s[tid]=bp[tid]; b1_s[tid]=b1[tid]; b2_s[tid]=b2[tid];
        g_s[tid]=g2[tid]; be_s[tid]=be2[tid];
    }
    __syncthreads();

    const int gid  = blockIdx.x * 256 + tid;
    const int row  = gid >> 1;
    const int half = gid & 1;
    const int b0   = half * 20;
    const int b    = row >> 11;
    const int t    = row & (TT-1);

    float cat[D];
    #pragma unroll
    for (int h = 0; h < NH; ++h) {
        const float2* ap = reinterpret_cast<const float2*>(
            attn + ((((size_t)b*NH + h)*TT) + t)*HS);
        #pragma unroll
        for (int e = 0; e < HS/2; ++e) {
            float2 t2 = ap[e];
            cat[h*HS + 2*e] = t2.x; cat[h*HS + 2*e + 1] = t2.y;
        }
    }

    float y[20];
    {
        const float4* xp = reinterpret_cast<const float4*>(xn + (size_t)row*D + b0);
        #pragma unroll
        for (int i = 0; i < 5; ++i) {
            float4 t4 = xp[i];
            y[4*i+0]=t4.x; y[4*i+1]=t4.y; y[4*i+2]=t4.z; y[4*i+3]=t4.w;
        }
    }
    #pragma unroll
    for (int d = 0; d < 20; ++d) y[d] += bp_s[b0+d];
    for (int c = 0; c < D; ++c) {
        const float cc = cat[c];
        const float4* wr = reinterpret_cast<const float4*>(&wp_s[c*D + b0]);
        #pragma unroll
        for (int i = 0; i < 5; ++i) {
            float4 t4 = wr[i];
            y[4*i+0] = fmaf(cc, t4.x, y[4*i+0]);
            y[4*i+1] = fmaf(cc, t4.y, y[4*i+1]);
            y[4*i+2] = fmaf(cc, t4.z, y[4*i+2]);
            y[4*i+3] = fmaf(cc, t4.w, y[4*i+3]);
        }
    }

    // LN2 via pairwise exchange
    float sp = 0.f;
    #pragma unroll
    for (int d = 0; d < 20; ++d) sp += y[d];
    const float mu = (sp + __shfl_xor(sp, 1)) * (1.f/D);
    float vp = 0.f;
    #pragma unroll
    for (int d = 0; d < 20; ++d) { float dd = y[d]-mu; vp += dd*dd; }
    const float var = (vp + __shfl_xor(vp, 1)) * (1.f/D);
    const float rs = rsqrtf(var + 1e-5f);

    float y2[20];
    #pragma unroll
    for (int d = 0; d < 20; ++d) y2[d] = (y[d]-mu)*rs*g_s[b0+d] + be_s[b0+d];

    float z[D];
    {
        const int ob0 = 20 - b0;
        #pragma unroll
        for (int d = 0; d < 20; ++d) {
            z[b0 + d]  = y2[d];
            z[ob0 + d] = __shfl_xor(y2[d], 1);
        }
    }

    float hd[20];
    #pragma unroll
    for (int d = 0; d < 20; ++d) hd[d] = b1_s[b0+d];
    for (int c = 0; c < D; ++c) {
        const float cc = z[c];
        const float4* wr = reinterpret_cast<const float4*>(&w1_s[c*D + b0]);
        #pragma unroll
        for (int i = 0; i < 5; ++i) {
            float4 t4 = wr[i];
            hd[4*i+0] = fmaf(cc, t4.x, hd[4*i+0]);
            hd[4*i+1] = fmaf(cc, t4.y, hd[4*i+1]);
            hd[4*i+2] = fmaf(cc, t4.z, hd[4*i+2]);
            hd[4*i+3] = fmaf(cc, t4.w, hd[4*i+3]);
        }
    }
    #pragma unroll
    for (int d = 0; d < 20; ++d) hd[d] = fmaxf(hd[d], 0.f);

    float hf[D];
    {
        const int ob0 = 20 - b0;
        #pragma unroll
        for (int d = 0; d < 20; ++d) {
            hf[b0 + d]  = hd[d];
            hf[ob0 + d] = __shfl_xor(hd[d], 1);
        }
    }

    float ov[20];
    #pragma unroll
    for (int d = 0; d < 20; ++d) ov[d] = y2[d] + b2_s[b0+d];
    for (int c = 0; c < D; ++c) {
        const float cc = hf[c];
        const float4* wr = reinterpret_cast<const float4*>(&w2_s[c*D + b0]);
        #pragma unroll
        for (int i = 0; i < 5; ++i) {
            float4 t4 = wr[i];
            ov[4*i+0] = fmaf(cc, t4.x, ov[4*i+0]);
            ov[4*i+1] = fmaf(cc, t4.y, ov[4*i+1]);
            ov[4*i+2] = fmaf(cc, t4.z, ov[4*i+2]);
            ov[4*i+3] = fmaf(cc, t4.w, ov[4*i+3]);
        }
    }

    float4* op = reinterpret_cast<float4*>(out + (size_t)row*D + b0);
    #pragma unroll
    for (int i = 0; i < 5; ++i) {
        float4 t4; t4.x=ov[4*i+0]; t4.y=ov[4*i+1]; t4.z=ov[4*i+2]; t4.w=ov[4*i+3];
        op[i] = t4;
    }
}

} // namespace

extern "C" void kernel_launch(void* const* d_in, const int* in_sizes, int n_in,
                              void* d_out, int out_size, void* d_ws, size_t ws_size,
                              hipStream_t stream) {
    const float* x   = (const float*)d_in[0];
    const float* Wq  = (const float*)d_in[1];
    const float* Wk  = (const float*)d_in[2];
    const float* Wv  = (const float*)d_in[3];
    const float* Wp  = (const float*)d_in[4];
    const float* bp  = (const float*)d_in[5];
    const float* W1  = (const float*)d_in[6];
    const float* b1  = (const float*)d_in[7];
    const float* W2  = (const float*)d_in[8];
    const float* b2  = (const float*)d_in[9];
    const float* g1  = (const float*)d_in[10];
    const float* be1 = (const float*)d_in[11];
    const float* g2  = (const float*)d_in[12];
    const float* be2 = (const float*)d_in[13];

    const size_t N = (size_t)ROWS * D;           // 1,310,720
    float* xn = (float*)d_ws;                    // [ROWS][40] f32
    float* ao = xn + N;                          // [64][2048][10] f32
    unsigned short* qb = (unsigned short*)(ao + N);        // [64][2048][16] bf16
    unsigned short* kb = qb + (size_t)BB*NH*TT*PE;
    unsigned short* vT = kb + (size_t)BB*NH*TT*PE;         // [64][11][2048] bf16

    k_ln_qkv<<<ROWS*4/256, 256, 0, stream>>>(x, Wq, Wk, Wv, g1, be1, xn, qb, kb, vT);
    k_attn<<<dim3(TT/64, BB*NH), 256, 0, stream>>>(qb, kb, vT, ao);
    k_epilogue<<<ROWS*2/256, 256, 0, stream>>>(ao, xn, Wp, bp, W1, b1, W2, b2, g2, be2,
                                               (float*)d_out);
}

// Round 9
// 117.198 us; speedup vs baseline: 1.0218x; 1.0218x over previous
//
#include <hip/hip_runtime.h>
#include <math.h>

namespace {

using bf16x8 = __attribute__((ext_vector_type(8))) short;
using f32x4  = __attribute__((ext_vector_type(4))) float;

constexpr int D   = 40;     // n_embed
constexpr int HS  = 10;     // head size
constexpr int NH  = 4;      // heads
constexpr int TT  = 2048;   // seq len
constexpr int BB  = 16;     // batch
constexpr int ROWS = BB * TT;       // 32768
constexpr int PE  = 16;             // padded head size for q/k bf16 rows
constexpr int VR  = 11;             // vT rows: 10 V + 1 ones (for l via MFMA)
constexpr float LOG2E = 1.4426950408889634f;

__device__ inline unsigned short f2b(float x) {   // fp32 -> bf16 RNE
    unsigned int u = __float_as_uint(x);
    unsigned int r = (u + 0x7fffu + ((u >> 16) & 1u)) >> 16;
    return (unsigned short)r;
}

__device__ inline f32x4 mfma32(bf16x8 a, bf16x8 b, f32x4 c) {
    return __builtin_amdgcn_mfma_f32_16x16x32_bf16(a, b, c, 0, 0, 0);
}

__device__ inline float dot40(const float* __restrict__ xr,
                              const float* __restrict__ w) {
    float s0 = 0.f, s1 = 0.f, s2 = 0.f, s3 = 0.f;
    const float4* w4 = reinterpret_cast<const float4*>(w);
    #pragma unroll
    for (int i = 0; i < 10; ++i) {
        float4 t = w4[i];
        s0 = fmaf(xr[4*i+0], t.x, s0);
        s1 = fmaf(xr[4*i+1], t.y, s1);
        s2 = fmaf(xr[4*i+2], t.z, s2);
        s3 = fmaf(xr[4*i+3], t.w, s3);
    }
    return (s0 + s1) + (s2 + s3);
}

// ------- Kernel 1: LN1 + QKV, 8 threads per row (head x e-half) -------------
__global__ __launch_bounds__(256) void k_ln_qkv(
    const float* __restrict__ x,  const float* __restrict__ Wq,
    const float* __restrict__ Wk, const float* __restrict__ Wv,
    const float* __restrict__ g1, const float* __restrict__ be1,
    float* __restrict__ xn, unsigned short* __restrict__ qb,
    unsigned short* __restrict__ kb, unsigned short* __restrict__ vT)
{
    __shared__ float wt_s[3*NH*HS*D];   // transposed: [which][h][e][d]
    __shared__ float g_s[D], b_s[D];
    const int tid = threadIdx.x;
    for (int i = tid; i < NH*D*HS; i += 256) {
        const int h = i / (D*HS), r = i % (D*HS);
        const int d = r / HS, e = r % HS;
        const int to = (h*HS + e)*D + d;
        wt_s[to]              = Wq[i];
        wt_s[NH*HS*D + to]    = Wk[i];
        wt_s[2*NH*HS*D + to]  = Wv[i];
    }
    if (tid < D) { g_s[tid] = g1[tid]; b_s[tid] = be1[tid]; }
    __syncthreads();

    const int gid = blockIdx.x * 256 + tid;
    const int eh  = gid & 1;            // e-half: 0 -> e 0..4, 1 -> e 5..9
    const int h   = (gid >> 1) & 3;
    const int row = gid >> 3;

    float xr[D];
    const float4* xp = reinterpret_cast<const float4*>(x + (size_t)row * D);
    #pragma unroll
    for (int i = 0; i < D/4; ++i) {
        float4 t4 = xp[i];
        xr[4*i+0]=t4.x; xr[4*i+1]=t4.y; xr[4*i+2]=t4.z; xr[4*i+3]=t4.w;
    }
    float mu = 0.f;
    #pragma unroll
    for (int d = 0; d < D; ++d) mu += xr[d];
    mu *= (1.f/D);
    float var = 0.f;
    #pragma unroll
    for (int d = 0; d < D; ++d) { float dd = xr[d]-mu; var += dd*dd; }
    var *= (1.f/D);
    const float rs = rsqrtf(var + 1e-5f);
    #pragma unroll
    for (int d = 0; d < D; ++d) xr[d] = (xr[d]-mu)*rs*g_s[d] + b_s[d];

    if ((gid & 7) == 0) {
        float4* xo = reinterpret_cast<float4*>(xn + (size_t)row * D);
        #pragma unroll
        for (int i = 0; i < D/4; ++i) {
            float4 t4; t4.x=xr[4*i+0]; t4.y=xr[4*i+1]; t4.z=xr[4*i+2]; t4.w=xr[4*i+3];
            xo[i] = t4;
        }
    }

    const int b = row >> 11;
    const int t = row & (TT-1);
    const int bh = b*NH + h;
    const int e0 = eh * 5;

    float aq[5], ak[5], av[5];
    #pragma unroll
    for (int e = 0; e < 5; ++e) {
        aq[e] = dot40(xr, &wt_s[(h*HS + e0 + e)*D]);
        ak[e] = dot40(xr, &wt_s[NH*HS*D + (h*HS + e0 + e)*D]);
        av[e] = dot40(xr, &wt_s[2*NH*HS*D + (h*HS + e0 + e)*D]);
    }

    // exchange: eh0 sends its k-lows (partner needs them), eh1 sends q-highs.
    float send[5], recv[5];
    #pragma unroll
    for (int j = 0; j < 5; ++j) send[j] = eh ? aq[j] : ak[j];
    #pragma unroll
    for (int j = 0; j < 5; ++j) recv[j] = __shfl_xor(send[j], 1);

    // eh0 owns the full q row (scaled by log2 e); eh1 owns the full k row
    const float scale = eh ? 1.f : LOG2E;
    float lo[5], hi[5];
    #pragma unroll
    for (int j = 0; j < 5; ++j) {
        lo[j] = eh ? recv[j] : aq[j];
        hi[j] = eh ? ak[j]   : recv[j];
    }
    union { unsigned short u[PE]; uint4 v4[2]; } U;
    #pragma unroll
    for (int e = 0; e < PE; ++e)
        U.u[e] = (e < 5) ? f2b(lo[e]*scale)
               : (e < 10) ? f2b(hi[e-5]*scale) : (unsigned short)0;
    unsigned short* dst = (eh ? kb : qb) + ((size_t)bh*TT + t)*PE;
    uint4* d4 = reinterpret_cast<uint4*>(dst);
    d4[0] = U.v4[0]; d4[1] = U.v4[1];

    #pragma unroll
    for (int e = 0; e < 5; ++e)
        vT[((size_t)bh*VR + e0 + e)*TT + t] = f2b(av[e]);
    if (eh) vT[((size_t)bh*VR + HS)*TT + t] = 0x3F80;   // ones row -> l via MFMA
}

// ------- Kernel 2: MFMA flash attention, software-pipelined ------------------
// Verified 16x16x32 layouts. Dual j-stream + explicit it+1 prefetch into
// separate named registers (forces live ranges -> loads overlap compute).
__global__ __launch_bounds__(256) void k_attn(
    const unsigned short* __restrict__ qb, const unsigned short* __restrict__ kb,
    const unsigned short* __restrict__ vT, float* __restrict__ ao)
{
    __shared__ __align__(16) unsigned short PT[4][2][16][40];
    const int w    = threadIdx.x >> 6;
    const int lane = threadIdx.x & 63;
    const int g    = lane >> 4;
    const int li   = lane & 15;
    const int bh   = blockIdx.y;
    const int i0   = blockIdx.x * 64 + w * 16;
    const size_t bT = (size_t)bh * TT;

    const bf16x8 zero8 = {0,0,0,0,0,0,0,0};
    const f32x4  zacc  = {0.f,0.f,0.f,0.f};

    bf16x8 kf = zero8;                       // B-frag: k[i0+li][8g..8g+7]
    if (g < 2) kf = *reinterpret_cast<const bf16x8*>(kb + (bT + i0 + li)*PE + 8*g);

    f32x4 accA = zacc, accB = zacc;
    const bool qok = (g < 2), vok = (li <= HS);
    const unsigned short* vrow = vT + ((size_t)bh*VR + (li <= HS ? li : 0))*TT;
    const unsigned short* qrow = qb + (bT + li)*PE + 8*g;

    // ---- prologue: load it=0 fragments ----
    bf16x8 a0A=zero8, a1A=zero8, a0B=zero8, a1B=zero8, vfA=zero8, vfB=zero8;
    if (qok) {
        a0A = *reinterpret_cast<const bf16x8*>(qrow);
        a1A = *reinterpret_cast<const bf16x8*>(qrow + (size_t)16*PE);
        a0B = *reinterpret_cast<const bf16x8*>(qrow + (size_t)(TT/2)*PE);
        a1B = *reinterpret_cast<const bf16x8*>(qrow + (size_t)(TT/2 + 16)*PE);
    }
    if (vok) {
        vfA = *reinterpret_cast<const bf16x8*>(vrow + 8*g);
        vfB = *reinterpret_cast<const bf16x8*>(vrow + TT/2 + 8*g);
    }

    for (int it = 0; it < TT/64; ++it) {     // 32 iterations, 64 j each
        const int nit = (it + 1) & (TT/64 - 1);   // wrap tail (values unused)
        const int njA = nit * 32;
        const int njB = njA + TT/2;

        // -------- scores (current) -----------------------------------------
        __builtin_amdgcn_s_setprio(1);
        f32x4 sA0 = mfma32(a0A, kf, zacc);
        f32x4 sA1 = mfma32(a1A, kf, zacc);
        f32x4 sB0 = mfma32(a0B, kf, zacc);
        f32x4 sB1 = mfma32(a1B, kf, zacc);
        __builtin_amdgcn_s_setprio(0);

        // -------- issue NEXT iteration's loads now (overlap with tail) -----
        bf16x8 n0A=zero8, n1A=zero8, n0B=zero8, n1B=zero8, nvA=zero8, nvB=zero8;
        if (qok) {
            n0A = *reinterpret_cast<const bf16x8*>(qrow + (size_t)(njA     )*PE);
            n1A = *reinterpret_cast<const bf16x8*>(qrow + (size_t)(njA + 16)*PE);
            n0B = *reinterpret_cast<const bf16x8*>(qrow + (size_t)(njB     )*PE);
            n1B = *reinterpret_cast<const bf16x8*>(qrow + (size_t)(njB + 16)*PE);
        }
        if (vok) {
            nvA = *reinterpret_cast<const bf16x8*>(vrow + njA + 8*g);
            nvB = *reinterpret_cast<const bf16x8*>(vrow + njB + 8*g);
        }

        // -------- exp2 + pack (q pre-scaled by log2 e) ---------------------
        const float pA0 = __builtin_amdgcn_exp2f(sA0[0]), pA1 = __builtin_amdgcn_exp2f(sA0[1]);
        const float pA2 = __builtin_amdgcn_exp2f(sA0[2]), pA3 = __builtin_amdgcn_exp2f(sA0[3]);
        const float pA4 = __builtin_amdgcn_exp2f(sA1[0]), pA5 = __builtin_amdgcn_exp2f(sA1[1]);
        const float pA6 = __builtin_amdgcn_exp2f(sA1[2]), pA7 = __builtin_amdgcn_exp2f(sA1[3]);
        const float pB0 = __builtin_amdgcn_exp2f(sB0[0]), pB1 = __builtin_amdgcn_exp2f(sB0[1]);
        const float pB2 = __builtin_amdgcn_exp2f(sB0[2]), pB3 = __builtin_amdgcn_exp2f(sB0[3]);
        const float pB4 = __builtin_amdgcn_exp2f(sB1[0]), pB5 = __builtin_amdgcn_exp2f(sB1[1]);
        const float pB6 = __builtin_amdgcn_exp2f(sB1[2]), pB7 = __builtin_amdgcn_exp2f(sB1[3]);

        unsigned int wA0,wA1,wA2,wA3, wB0,wB1,wB2,wB3;
        asm("v_cvt_pk_bf16_f32 %0, %1, %2" : "=v"(wA0) : "v"(pA0), "v"(pA1));
        asm("v_cvt_pk_bf16_f32 %0, %1, %2" : "=v"(wA1) : "v"(pA2), "v"(pA3));
        asm("v_cvt_pk_bf16_f32 %0, %1, %2" : "=v"(wA2) : "v"(pA4), "v"(pA5));
        asm("v_cvt_pk_bf16_f32 %0, %1, %2" : "=v"(wA3) : "v"(pA6), "v"(pA7));
        asm("v_cvt_pk_bf16_f32 %0, %1, %2" : "=v"(wB0) : "v"(pB0), "v"(pB1));
        asm("v_cvt_pk_bf16_f32 %0, %1, %2" : "=v"(wB1) : "v"(pB2), "v"(pB3));
        asm("v_cvt_pk_bf16_f32 %0, %1, %2" : "=v"(wB2) : "v"(pB4), "v"(pB5));
        asm("v_cvt_pk_bf16_f32 %0, %1, %2" : "=v"(wB3) : "v"(pB6), "v"(pB7));

        // -------- P^T bounce: wave-private LDS, in-order DS => no barrier ---
        *reinterpret_cast<uint2*>(&PT[w][0][li][4*g])      = make_uint2(wA0, wA1);
        *reinterpret_cast<uint2*>(&PT[w][0][li][16 + 4*g]) = make_uint2(wA2, wA3);
        *reinterpret_cast<uint2*>(&PT[w][1][li][4*g])      = make_uint2(wB0, wB1);
        *reinterpret_cast<uint2*>(&PT[w][1][li][16 + 4*g]) = make_uint2(wB2, wB3);

        bf16x8 pfA = *reinterpret_cast<const bf16x8*>(&PT[w][0][li][8*g]);
        bf16x8 pfB = *reinterpret_cast<const bf16x8*>(&PT[w][1][li][8*g]);

        // -------- PV (current) ---------------------------------------------
        __builtin_amdgcn_s_setprio(1);
        accA = mfma32(vfA, pfA, accA);       // O^T[e=4g+r][i0+li]
        accB = mfma32(vfB, pfB, accB);
        __builtin_amdgcn_s_setprio(0);

        // -------- rotate pipeline registers --------------------------------
        a0A = n0A; a1A = n1A; a0B = n0B; a1B = n1B; vfA = nvA; vfB = nvB;
    }

    const f32x4 acc = accA + accB;
    // l for column li = O^T row 10 = lane (g=2, li), reg 2
    const float l = __shfl(acc[2], 32 + li);
    const float linv = 1.f / l;
    float* orow = ao + (bT + i0 + li) * HS;
    #pragma unroll
    for (int r = 0; r < 4; ++r) {
        const int e = 4*g + r;
        if (e < HS) orow[e] = acc[r] * linv;
    }
}

// ------- Kernel 3: epilogue, 4 threads per row ------------------------------
__global__ __launch_bounds__(256) void k_epilogue(
    const float* __restrict__ attn, const float* __restrict__ xn,
    const float* __restrict__ Wp, const float* __restrict__ bp,
    const float* __restrict__ W1, const float* __restrict__ b1,
    const float* __restrict__ W2, const float* __restrict__ b2,
    const float* __restrict__ g2, const float* __restrict__ be2,
    float* __restrict__ out)
{
    __shared__ float wp_s[D*D], w1_s[D*D], w2_s[D*D];
    __shared__ float bp_s[D], b1_s[D], b2_s[D], g_s[D], be_s[D];
    const int tid = threadIdx.x;
    for (int i = tid; i < D*D; i += 256) { wp_s[i]=Wp[i]; w1_s[i]=W1[i]; w2_s[i]=W2[i]; }
    if (tid < D) {
        bp_s[tid]=bp[tid]; b1_s[tid]=b1[tid]; b2_s[tid]=b2[tid];
        g_s[tid]=g2[tid]; be_s[tid]=be2[tid];
    }
    __syncthreads();

    const int gid  = blockIdx.x * 256 + tid;
    const int row  = gid >> 2;
    const int q4   = gid & 3;
    const int b0   = q4 * 10;
    const int lane = tid & 63;
    const int base = lane & 60;          // first lane of this row's 4-lane group
    const int b    = row >> 11;
    const int t    = row & (TT-1);

    float cat[D];
    #pragma unroll
    for (int h = 0; h < NH; ++h) {
        const float2* ap = reinterpret_cast<const float2*>(
            attn + ((((size_t)b*NH + h)*TT) + t)*HS);
        #pragma unroll
        for (int e = 0; e < HS/2; ++e) {
            float2 t2 = ap[e];
            cat[h*HS + 2*e] = t2.x; cat[h*HS + 2*e + 1] = t2.y;
        }
    }

    float y[10];
    {
        const float2* xp = reinterpret_cast<const float2*>(xn + (size_t)row*D + b0);
        #pragma unroll
        for (int i = 0; i < 5; ++i) {
            float2 t2 = xp[i];
            y[2*i+0] = t2.x; y[2*i+1] = t2.y;
        }
    }
    #pragma unroll
    for (int d = 0; d < 10; ++d) y[d] += bp_s[b0+d];
    for (int c = 0; c < D; ++c) {
        const float cc = cat[c];
        const float* wr = &wp_s[c*D + b0];
        #pragma unroll
        for (int d = 0; d < 10; ++d) y[d] = fmaf(cc, wr[d], y[d]);
    }

    // LN2 via 4-lane reduce
    float sp = 0.f;
    #pragma unroll
    for (int d = 0; d < 10; ++d) sp += y[d];
    sp += __shfl_xor(sp, 1); sp += __shfl_xor(sp, 2);
    const float mu = sp * (1.f/D);
    float vp = 0.f;
    #pragma unroll
    for (int d = 0; d < 10; ++d) { float dd = y[d]-mu; vp += dd*dd; }
    vp += __shfl_xor(vp, 1); vp += __shfl_xor(vp, 2);
    const float rs = rsqrtf(vp * (1.f/D) + 1e-5f);

    float y2[10];
    #pragma unroll
    for (int d = 0; d < 10; ++d) y2[d] = (y[d]-mu)*rs*g_s[b0+d] + be_s[b0+d];

    float z[D];
    #pragma unroll
    for (int seg = 0; seg < 4; ++seg)
        #pragma unroll
        for (int j = 0; j < 10; ++j)
            z[seg*10 + j] = __shfl(y2[j], base + seg);

    float hd[10];
    #pragma unroll
    for (int d = 0; d < 10; ++d) hd[d] = b1_s[b0+d];
    for (int c = 0; c < D; ++c) {
        const float cc = z[c];
        const float* wr = &w1_s[c*D + b0];
        #pragma unroll
        for (int d = 0; d < 10; ++d) hd[d] = fmaf(cc, wr[d], hd[d]);
    }
    #pragma unroll
    for (int d = 0; d < 10; ++d) hd[d] = fmaxf(hd[d], 0.f);

    float hf[D];
    #pragma unroll
    for (int seg = 0; seg < 4; ++seg)
        #pragma unroll
        for (int j = 0; j < 10; ++j)
            hf[seg*10 + j] = __shfl(hd[j], base + seg);

    float ov[10];
    #pragma unroll
    for (int d = 0; d < 10; ++d) ov[d] = y2[d] + b2_s[b0+d];
    for (int c = 0; c < D; ++c) {
        const float cc = hf[c];
        const float* wr = &w2_s[c*D + b0];
        #pragma unroll
        for (int d = 0; d < 10; ++d) ov[d] = fmaf(cc, wr[d], ov[d]);
    }

    float2* op = reinterpret_cast<float2*>(out + (size_t)row*D + b0);
    #pragma unroll
    for (int i = 0; i < 5; ++i) {
        float2 t2; t2.x = ov[2*i]; t2.y = ov[2*i+1];
        op[i] = t2;
    }
}

} // namespace

extern "C" void kernel_launch(void* const* d_in, const int* in_sizes, int n_in,
                              void* d_out, int out_size, void* d_ws, size_t ws_size,
                              hipStream_t stream) {
    const float* x   = (const float*)d_in[0];
    const float* Wq  = (const float*)d_in[1];
    const float* Wk  = (const float*)d_in[2];
    const float* Wv  = (const float*)d_in[3];
    const float* Wp  = (const float*)d_in[4];
    const float* bp  = (const float*)d_in[5];
    const float* W1  = (const float*)d_in[6];
    const float* b1  = (const float*)d_in[7];
    const float* W2  = (const float*)d_in[8];
    const float* b2  = (const float*)d_in[9];
    const float* g1  = (const float*)d_in[10];
    const float* be1 = (const float*)d_in[11];
    const float* g2  = (const float*)d_in[12];
    const float* be2 = (const float*)d_in[13];

    const size_t N = (size_t)ROWS * D;           // 1,310,720
    float* xn = (float*)d_ws;                    // [ROWS][40] f32
    float* ao = xn + N;                          // [64][2048][10] f32
    unsigned short* qb = (unsigned short*)(ao + N);        // [64][2048][16] bf16
    unsigned short* kb = qb + (size_t)BB*NH*TT*PE;
    unsigned short* vT = kb + (size_t)BB*NH*TT*PE;         // [64][11][2048] bf16

    k_ln_qkv<<<ROWS*8/256, 256, 0, stream>>>(x, Wq, Wk, Wv, g1, be1, xn, qb, kb, vT);
    k_attn<<<dim3(TT/64, BB*NH), 256, 0, stream>>>(qb, kb, vT, ao);
    k_epilogue<<<ROWS*4/256, 256, 0, stream>>>(ao, xn, Wp, bp, W1, b1, W2, b2, g2, be2,
                                               (float*)d_out);
}